// Round 9
// baseline (4368.217 us; speedup 1.0000x reference)
//
#include <hip/hip_runtime.h>

typedef __bf16 bf16x8 __attribute__((ext_vector_type(8)));
typedef float f32x4 __attribute__((ext_vector_type(4)));
typedef unsigned long long u64;

__device__ inline float sigm(float x) { return 1.0f / (1.0f + __expf(-x)); }
__device__ inline float tanh_f(float x) {
    float e = __expf(2.0f * x);
    return 1.0f - 2.0f / (e + 1.0f);
}

__device__ inline unsigned short f2bf(float f) {
    __bf16 h = (__bf16)f;
    return __builtin_bit_cast(unsigned short, h);
}

__device__ inline bf16x8 cvt8(float4 lo, float4 hi) {
    bf16x8 r;
    r[0] = (__bf16)lo.x; r[1] = (__bf16)lo.y; r[2] = (__bf16)lo.z; r[3] = (__bf16)lo.w;
    r[4] = (__bf16)hi.x; r[5] = (__bf16)hi.y; r[6] = (__bf16)hi.z; r[7] = (__bf16)hi.w;
    return r;
}

// compiler-visible LLC-coherent ops (sc0 sc1, no fences, counted vmcnt)
__device__ inline u64 ld64c(const u64* p) {
    return __hip_atomic_load(p, __ATOMIC_RELAXED, __HIP_MEMORY_SCOPE_AGENT);
}
__device__ inline void st32c(unsigned int* p, unsigned int v) {
    __hip_atomic_store(p, v, __ATOMIC_RELAXED, __HIP_MEMORY_SCOPE_AGENT);
}
__device__ inline unsigned int ld32c(const unsigned int* p) {
    return __hip_atomic_load(p, __ATOMIC_RELAXED, __HIP_MEMORY_SCOPE_AGENT);
}

// ---------------------------------------------------------------------------
// FRAGMENT-MAJOR tile format for all 32x1024 bf16 A-tiles (h and seqb):
//   u16 offset F(row, col) = (row>>4)*16384 + (col>>5)*512
//                          + (((col>>3)&3)*16 + (row&15))*8 + (col&7)
// Consumers copy tiles LINEARLY (coalesced 16B/lane) and MFMA-read linearly
// (tile + kk*512 + lane*8) -> zero LDS bank conflicts by construction.
// ---------------------------------------------------------------------------

// Weight conversion: W{x,h}{0,1} fp32 [4096][1024] -> Wcat bf16 [4096][2048]
__global__ void cvt_weights(const float* __restrict__ Wx0, const float* __restrict__ Wh0,
                            const float* __restrict__ Wx1, const float* __restrict__ Wh1,
                            unsigned short* __restrict__ W0, unsigned short* __restrict__ W1) {
    size_t idx = ((size_t)blockIdx.x * 256 + threadIdx.x) * 8;
    const size_t LSZ = (size_t)4096 * 2048;
    int layer = idx >= LSZ;
    size_t e = idx - (layer ? LSZ : 0);
    int row = (int)(e >> 11);
    int k = (int)(e & 2047);
    const float* src = layer ? (k < 1024 ? Wx1 : Wh1) : (k < 1024 ? Wx0 : Wh0);
    const float* s = src + (size_t)row * 1024 + (k & 1023);
    float4 lo = ((const float4*)s)[0], hi = ((const float4*)s)[1];
    *reinterpret_cast<bf16x8*>((layer ? W1 : W0) + e) = cvt8(lo, hi);
}

// sequence [B][T][I] fp32 -> seqb [T][btile][fragment-major 32x1024 tile] bf16
__global__ void cvt_seq(const float* __restrict__ seq, unsigned short* __restrict__ seqb, int T) {
    int t = blockIdx.x >> 6, b = blockIdx.x & 63;
    int row = b & 31, btile = b >> 5, tid = threadIdx.x;  // 128 threads, 8 cols each
    const float* s = seq + ((size_t)b * T + t) * 1024 + tid * 8;
    float4 lo = ((const float4*)s)[0], hi = ((const float4*)s)[1];
    int off = ((row >> 4) << 14) + ((tid >> 2) << 9) + (((tid & 3) << 4) + (row & 15)) * 8;
    *reinterpret_cast<bf16x8*>(seqb + ((size_t)t * 2 + btile) * 32768 + off) = cvt8(lo, hi);
}

// ---------------------------------------------------------------------------
// LDS: two A tiles (64 KB each, fragment-major, linear);
// z-exchange aliases tile a[0] (safe: all pass0 reads of a[0] complete before
// the post-stage1-write sync, which precedes any z write).
// ---------------------------------------------------------------------------
union SmemU {
    unsigned short a[2][32768];  // 128 KB
    float z[4][32][16];          // 8 KB (aliases a[0])
};

struct StageRegs { u64 q[32]; };  // 64 VGPRs, only one live at a time

__device__ inline void stage_issue(StageRegs& r, const unsigned short* __restrict__ src) {
#pragma unroll
    for (int i = 0; i < 16; ++i) {
        const u64* s = (const u64*)(src + (size_t)((threadIdx.x + (i << 8)) << 3));
        r.q[2 * i] = ld64c(s);
        r.q[2 * i + 1] = ld64c(s + 1);
    }
}

__device__ inline void stage_issue_plain(StageRegs& r, const unsigned short* __restrict__ src) {
#pragma unroll
    for (int i = 0; i < 16; ++i) {
        const u64* s = (const u64*)(src + (size_t)((threadIdx.x + (i << 8)) << 3));
        r.q[2 * i] = s[0];
        r.q[2 * i + 1] = s[1];
    }
}

__device__ inline void stage_write(const StageRegs& r, unsigned short* tile) {
#pragma unroll
    for (int i = 0; i < 16; ++i) {
        u64* d = (u64*)(tile + (size_t)((threadIdx.x + (i << 8)) << 3));
        d[0] = r.q[2 * i];
        d[1] = r.q[2 * i + 1];
    }
}

// MFMA K=1024 pass: A linear fragment-major LDS, B from persistent registers.
template <int BASE>
__device__ inline void mfma_pass(const unsigned short* tile, const bf16x8 (&w)[64],
                                 f32x4& acc0, f32x4& acc1, int lane) {
#pragma unroll
    for (int kk = 0; kk < 32; ++kk) {
        bf16x8 av0 = *(const bf16x8*)(tile + kk * 512 + lane * 8);
        bf16x8 av1 = *(const bf16x8*)(tile + 16384 + kk * 512 + lane * 8);
        acc0 = __builtin_amdgcn_mfma_f32_16x16x32_bf16(av0, w[BASE + kk], acc0, 0, 0, 0);
        acc1 = __builtin_amdgcn_mfma_f32_16x16x32_bf16(av1, w[BASE + kk], acc1, 0, 0, 0);
    }
}

// ---------------------------------------------------------------------------
// Persistent skew-2 pipelined 2-layer LSTM, FULL weight panel in registers.
// Phase structure (4 block-syncs, stage0 RT hidden under the flag spin):
//   issue s0 -> per-thread spin(resolve p-1) -> write s0 -> SYNC ->
//   issue s1 -> pass0 (covers s1 RT) -> write s1 -> SYNC -> pass1 ->
//   z-write -> SYNC -> epilogue/h-store -> SYNC -> publish flag
// ---------------------------------------------------------------------------
template <bool SEQB>
__global__ __launch_bounds__(256, 1) void lstm_persistent(
    const float* __restrict__ seq, const unsigned short* __restrict__ seqb,
    const unsigned short* __restrict__ W0, const unsigned short* __restrict__ W1,
    const float* __restrict__ bias0, const float* __restrict__ bias1,
    unsigned short* h0buf, unsigned short* h1buf, unsigned int* flags,
    float* out, int T) {
    const int bid = blockIdx.x;
    const int r = bid & 7, q = bid >> 3;
    const int btile = q & 1, t2 = q >> 1;
    const int layer = t2 >> 3;
    const int jtile = ((t2 & 7) << 3) | r;
    const int j0 = jtile * 16;
    const int brow = btile * 32;

    const int tid = threadIdx.x;
    const int wave = tid >> 6, lane = tid & 63;
    const int ln15 = lane & 15, lhi = lane >> 4;

    const unsigned short* Wl = layer ? W1 : W0;
    const float* bias = layer ? bias1 : bias0;
    const unsigned short* Bbase = Wl + (size_t)(wave * 1024 + j0 + ln15) * 2048 + lhi * 8;
    unsigned short* hown = layer ? h1buf : h0buf;

    __shared__ SmemU smem;

    // ---- persistent weight panel: 64 x bf16x8 = 256 VGPRs per lane ----
    bf16x8 wreg[64];
#pragma unroll
    for (int q2 = 0; q2 < 64; ++q2)
        wreg[q2] = *reinterpret_cast<const bf16x8*>(Bbase + q2 * 32);

    // epilogue mapping: thread -> (bl, jj), handles cols jj, jj+1
    const int bl = tid >> 3;
    const int jj = (tid & 7) * 2;
    const float bf0 = bias[j0 + jj],        bf1 = bias[j0 + jj + 1];
    const float bw0 = bias[1024 + j0 + jj], bw1 = bias[1024 + j0 + jj + 1];
    const float bi0 = bias[2048 + j0 + jj], bi1 = bias[2048 + j0 + jj + 1];
    const float bm0 = bias[3072 + j0 + jj], bm1 = bias[3072 + j0 + jj + 1];
    // fragment-major u16 offset within the destination h-tile
    const int colg = j0 + jj;
    const int hoff = ((bl >> 4) << 14) + ((colg >> 5) << 9) +
                     ((((colg >> 3) & 3) << 4) + (bl & 15)) * 8 + (colg & 7);

    float creg0 = 0.f, creg1 = 0.f;
    const int P = T + 2;

    for (int p = 0; p < P; ++p) {
        const bool act = layer ? (p >= 2) : (p < T);
        const int t = layer ? (p - 2) : p;
        const bool have0 = act && (layer == 1 || SEQB);

        // ---- issue stage0 loads (x-tile; data confirmed a phase ago) ----
        StageRegs s0;
        if (have0) {
            if (layer == 0)
                stage_issue_plain(s0, seqb + ((size_t)t * 2 + btile) * 32768);
            else
                stage_issue(s0, h0buf + (size_t)((t % 3) * 2 + btile) * 32768);
        }

        // ---- resolve barrier for phase p-1: independent per-thread spin.
        // (vmcnt ordering: first flag-read also drains s0 -> RT hidden here)
        if (p > 0) {
            const unsigned int tgt = (unsigned int)p;
            while (ld32c(&flags[tid]) < tgt) __builtin_amdgcn_s_sleep(1);
        }
        if (have0) stage_write(s0, smem.a[0]);
        __syncthreads();  // joins spin (all 256 flags confirmed) + a[0] visible

        if (act) {
            f32x4 acc0 = {0.f, 0.f, 0.f, 0.f};
            f32x4 acc1 = {0.f, 0.f, 0.f, 0.f};

            // ---- stage1 issue: own-layer h-prev (needs phase p-1 results) ----
            StageRegs s1;
            const unsigned short* hsrc = layer
                ? h1buf + (size_t)(((t + 1) & 1) * 2 + btile) * 32768   // h1[t-1]
                : h0buf + (size_t)(((t + 2) % 3) * 2 + btile) * 32768;  // h0[t-1]
            stage_issue(s1, hsrc);

            // ---- pass 0: x-part (covers stage1 latency) ----
            if (layer == 0 && !SEQB) {
                const float* a0f = seq + ((size_t)(brow + ln15) * T + t) * 1024 + lhi * 8;
                const float* a1f = a0f + (size_t)16 * T * 1024;
#pragma unroll
                for (int kk = 0; kk < 32; ++kk) {
                    float4 l0 = ((const float4*)a0f)[0], h0v = ((const float4*)a0f)[1];
                    float4 l1 = ((const float4*)a1f)[0], h1v = ((const float4*)a1f)[1];
                    bf16x8 av0 = cvt8(l0, h0v), av1 = cvt8(l1, h1v);
                    acc0 = __builtin_amdgcn_mfma_f32_16x16x32_bf16(av0, wreg[kk], acc0, 0, 0, 0);
                    acc1 = __builtin_amdgcn_mfma_f32_16x16x32_bf16(av1, wreg[kk], acc1, 0, 0, 0);
                    a0f += 32; a1f += 32;
                }
            } else {
                mfma_pass<0>(smem.a[0], wreg, acc0, acc1, lane);
            }

            // ---- pass 1: h-part ----
            stage_write(s1, smem.a[1]);
            __syncthreads();  // also proves: every wave finished pass0 (a[0] free)
            mfma_pass<32>(smem.a[1], wreg, acc0, acc1, lane);

            // ---- z-exchange into a[0]-aliased buffer (no extra sync needed:
            //      pass1 reads a[1]; a[0] reads all completed pre-sync above) ----
#pragma unroll
            for (int rr = 0; rr < 4; ++rr) {
                smem.z[wave][4 * lhi + rr][ln15] = acc0[rr];
                smem.z[wave][16 + 4 * lhi + rr][ln15] = acc1[rr];
            }
            __syncthreads();

            {
                float2 zf = *(const float2*)&smem.z[0][bl][jj];
                float2 zw = *(const float2*)&smem.z[1][bl][jj];
                float2 zi = *(const float2*)&smem.z[2][bl][jj];
                float2 zm = *(const float2*)&smem.z[3][bl][jj];
                float c0n = creg0 * sigm(zf.x + bf0) + sigm(zw.x + bw0) * tanh_f(zi.x + bi0);
                float c1n = creg1 * sigm(zf.y + bf1) + sigm(zw.y + bw1) * tanh_f(zi.y + bi1);
                float h0v = tanh_f(c0n) * sigm(zm.x + bm0);
                float h1v = tanh_f(c1n) * sigm(zm.y + bm1);
                creg0 = c0n; creg1 = c1n;
                const int wbuf = layer ? (t & 1) : (t % 3);
                unsigned short* tb = hown + (size_t)(wbuf * 2 + btile) * 32768;
                unsigned int packed = (unsigned int)f2bf(h0v) | ((unsigned int)f2bf(h1v) << 16);
                st32c((unsigned int*)(tb + hoff), packed);
                if (layer && t == T - 1) {
                    int idx = (brow + bl) * 1024 + colg;
                    out[idx] = h0v; out[idx + 1] = h1v;
                }
            }
        }

        // ---- publish phase completion ----
        if (p < P - 1) {
            __syncthreads();  // drains vmcnt: h-stores LLC-visible; WAR fence for a/z
            if (tid == 0) st32c(&flags[bid], (unsigned int)(p + 1));
        }
    }
}

// ---------------------------------------------------------------------------
extern "C" void kernel_launch(void* const* d_in, const int* in_sizes, int n_in,
                              void* d_out, int out_size, void* d_ws, size_t ws_size,
                              hipStream_t stream) {
    const float* seq = (const float*)d_in[0];
    const float* Wx0 = (const float*)d_in[1];
    const float* Wh0 = (const float*)d_in[2];
    const float* b0 = (const float*)d_in[3];
    const float* Wx1 = (const float*)d_in[4];
    const float* Wh1 = (const float*)d_in[5];
    const float* b1 = (const float*)d_in[6];
    float* out = (float*)d_out;
    char* ws = (char*)d_ws;
    const int T = 512;

    const size_t WBYTES = (size_t)4096 * 2048 * 2;         // 16.78 MB per layer
    const size_t SEQB_BYTES = (size_t)512 * 2 * 32768 * 2; // 67.1 MB (tile-major)
    const size_t H0_BYTES = 3 * 2 * 65536;                  // 3 bufs x 2 btiles
    const size_t H1_BYTES = 2 * 2 * 65536;
    const size_t STATE_BYTES = H0_BYTES + H1_BYTES + 1024;  // + flags

    size_t offSeqb = 2 * WBYTES;
    bool big = ws_size >= 2 * WBYTES + SEQB_BYTES + STATE_BYTES;
    size_t offState = big ? (offSeqb + SEQB_BYTES) : offSeqb;

    unsigned short* W0p = (unsigned short*)(ws);
    unsigned short* W1p = (unsigned short*)(ws + WBYTES);
    unsigned short* seqbp = (unsigned short*)(ws + offSeqb);
    unsigned short* h0p = (unsigned short*)(ws + offState);
    unsigned short* h1p = (unsigned short*)(ws + offState + H0_BYTES);
    unsigned int* flagsp = (unsigned int*)(ws + offState + H0_BYTES + H1_BYTES);

    hipLaunchKernelGGL(cvt_weights, dim3(8192), dim3(256), 0, stream,
                       Wx0, Wh0, Wx1, Wh1, W0p, W1p);
    if (big)
        hipLaunchKernelGGL(cvt_seq, dim3(T * 64), dim3(128), 0, stream, seq, seqbp, T);
    hipMemsetAsync(ws + offState, 0, STATE_BYTES, stream);

    int Tv = T;
    void* args[] = {&seq, &seqbp, &W0p, &W1p, &b0, &b1, &h0p, &h1p, &flagsp, &out, &Tv};
    if (big) {
        hipError_t e = hipLaunchCooperativeKernel((void*)lstm_persistent<true>,
                                                  dim3(256), dim3(256), args, 0, stream);
        if (e != hipSuccess) {
            // co-residency guaranteed by capacity (1 block/CU, 256 blocks);
            // the custom flag barrier needs no cooperative-launch semantics.
            hipLaunchKernelGGL((lstm_persistent<true>), dim3(256), dim3(256), 0, stream,
                               seq, seqbp, W0p, W1p, b0, b1, h0p, h1p, flagsp, out, Tv);
        }
    } else {
        hipError_t e = hipLaunchCooperativeKernel((void*)lstm_persistent<false>,
                                                  dim3(256), dim3(256), args, 0, stream);
        if (e != hipSuccess) {
            hipLaunchKernelGGL((lstm_persistent<false>), dim3(256), dim3(256), 0, stream,
                               seq, seqbp, W0p, W1p, b0, b1, h0p, h1p, flagsp, out, Tv);
        }
    }
}

// Round 10
// 3744.102 us; speedup vs baseline: 1.1667x; 1.1667x over previous
//
#include <hip/hip_runtime.h>

typedef __bf16 bf16x8 __attribute__((ext_vector_type(8)));
typedef float f32x4 __attribute__((ext_vector_type(4)));
typedef unsigned long long u64;

__device__ inline float sigm(float x) { return 1.0f / (1.0f + __expf(-x)); }
__device__ inline float tanh_f(float x) {
    float e = __expf(2.0f * x);
    return 1.0f - 2.0f / (e + 1.0f);
}

__device__ inline unsigned short f2bf(float f) {
    __bf16 h = (__bf16)f;
    return __builtin_bit_cast(unsigned short, h);
}

__device__ inline bf16x8 cvt8(float4 lo, float4 hi) {
    bf16x8 r;
    r[0] = (__bf16)lo.x; r[1] = (__bf16)lo.y; r[2] = (__bf16)lo.z; r[3] = (__bf16)lo.w;
    r[4] = (__bf16)hi.x; r[5] = (__bf16)hi.y; r[6] = (__bf16)hi.z; r[7] = (__bf16)hi.w;
    return r;
}

// compiler-visible LLC-coherent ops (sc0 sc1, no fences, counted vmcnt)
__device__ inline u64 ld64c(const u64* p) {
    return __hip_atomic_load(p, __ATOMIC_RELAXED, __HIP_MEMORY_SCOPE_AGENT);
}
__device__ inline void st32c(unsigned int* p, unsigned int v) {
    __hip_atomic_store(p, v, __ATOMIC_RELAXED, __HIP_MEMORY_SCOPE_AGENT);
}
__device__ inline unsigned int ld32c(const unsigned int* p) {
    return __hip_atomic_load(p, __ATOMIC_RELAXED, __HIP_MEMORY_SCOPE_AGENT);
}
__device__ inline void st16c(unsigned short* p, unsigned short v) {
    __hip_atomic_store(p, v, __ATOMIC_RELAXED, __HIP_MEMORY_SCOPE_AGENT);
}

// ---------------------------------------------------------------------------
// FRAGMENT-MAJOR tile format for all 32x1024 bf16 A-tiles (h and seqb):
//   u16 offset F(row, col) = (row>>4)*16384 + (col>>5)*512
//                          + (((col>>3)&3)*16 + (row&15))*8 + (col&7)
// Linear 16B/lane copies + linear MFMA reads -> zero bank conflicts.
// ---------------------------------------------------------------------------

// Weight conversion: W{x,h}{0,1} fp32 [4096][1024] -> Wcat bf16 [4096][2048]
__global__ void cvt_weights(const float* __restrict__ Wx0, const float* __restrict__ Wh0,
                            const float* __restrict__ Wx1, const float* __restrict__ Wh1,
                            unsigned short* __restrict__ W0, unsigned short* __restrict__ W1) {
    size_t idx = ((size_t)blockIdx.x * 256 + threadIdx.x) * 8;
    const size_t LSZ = (size_t)4096 * 2048;
    int layer = idx >= LSZ;
    size_t e = idx - (layer ? LSZ : 0);
    int row = (int)(e >> 11);
    int k = (int)(e & 2047);
    const float* src = layer ? (k < 1024 ? Wx1 : Wh1) : (k < 1024 ? Wx0 : Wh0);
    const float* s = src + (size_t)row * 1024 + (k & 1023);
    float4 lo = ((const float4*)s)[0], hi = ((const float4*)s)[1];
    *reinterpret_cast<bf16x8*>((layer ? W1 : W0) + e) = cvt8(lo, hi);
}

// sequence [B][T][I] fp32 -> seqb [T][btile][fragment-major 32x1024 tile] bf16
__global__ void cvt_seq(const float* __restrict__ seq, unsigned short* __restrict__ seqb, int T) {
    int t = blockIdx.x >> 6, b = blockIdx.x & 63;
    int row = b & 31, btile = b >> 5, tid = threadIdx.x;  // 128 threads, 8 cols each
    const float* s = seq + ((size_t)b * T + t) * 1024 + tid * 8;
    float4 lo = ((const float4*)s)[0], hi = ((const float4*)s)[1];
    int off = ((row >> 4) << 14) + ((tid >> 2) << 9) + (((tid & 3) << 4) + (row & 15)) * 8;
    *reinterpret_cast<bf16x8*>(seqb + ((size_t)t * 2 + btile) * 32768 + off) = cvt8(lo, hi);
}

// ---------------------------------------------------------------------------
// LDS: separate x/h A-tiles + zx double buffer + zh exchange (152 KB).
// ---------------------------------------------------------------------------
struct Smem {
    unsigned short ah[32768];   // 64 KB  h-team A-tile
    unsigned short ax[32768];   // 64 KB  x-team A-tile
    float zh[4][32][16];        // 8 KB   h-team gate exchange
    float zx[2][4][32][16];     // 16 KB  x-projection double buffer
};

struct StageRegs { u64 q[32]; };  // 64 VGPRs

__device__ inline void stage_issue(StageRegs& r, const unsigned short* __restrict__ src, int ttid) {
#pragma unroll
    for (int i = 0; i < 16; ++i) {
        const u64* s = (const u64*)(src + (size_t)((ttid + (i << 8)) << 3));
        r.q[2 * i] = ld64c(s);
        r.q[2 * i + 1] = ld64c(s + 1);
    }
}
__device__ inline void stage_issue_plain(StageRegs& r, const unsigned short* __restrict__ src, int ttid) {
#pragma unroll
    for (int i = 0; i < 16; ++i) {
        const u64* s = (const u64*)(src + (size_t)((ttid + (i << 8)) << 3));
        r.q[2 * i] = s[0];
        r.q[2 * i + 1] = s[1];
    }
}
__device__ inline void stage_write(const StageRegs& r, unsigned short* tile, int ttid) {
#pragma unroll
    for (int i = 0; i < 16; ++i) {
        u64* d = (u64*)(tile + (size_t)((ttid + (i << 8)) << 3));
        d[0] = r.q[2 * i];
        d[1] = r.q[2 * i + 1];
    }
}

// ---------------------------------------------------------------------------
// Persistent 2-layer LSTM with PRODUCER/CONSUMER WAVE SPECIALIZATION.
// 256 blocks x 512 threads (8 waves: 4 x-team + 4 h-team, 2 waves/SIMD).
// x-team computes zx[t+1] (no fresh deps for L0; 2-stale h0 for L1) into LDS;
// h-team runs the latency chain: h-stage -> K=1024 h-GEMM -> epilogue.
// Timesteps: L0: tx=p, th=p-1.  L1: tx=p-2, th=p-3.  P=T+3.
// Flags: per-block phase counters; groups G0=bids[0,128), G1=[128,256).
// ---------------------------------------------------------------------------
template <bool SEQB>
__global__ __launch_bounds__(512, 2) void lstm_persistent(
    const float* __restrict__ seq, const unsigned short* __restrict__ seqb,
    const unsigned short* __restrict__ W0, const unsigned short* __restrict__ W1,
    const float* __restrict__ bias0, const float* __restrict__ bias1,
    unsigned short* h0buf, unsigned short* h1buf, unsigned int* flags,
    float* out, int T) {
    const int bid = blockIdx.x;
    const int r = bid & 7, q = bid >> 3;
    const int btile = q & 1, t2 = q >> 1;
    const int layer = t2 >> 3;             // == bid>>7
    const int jtile = ((t2 & 7) << 3) | r;
    const int j0 = jtile * 16;
    const int brow = btile * 32;

    const int tid = threadIdx.x;           // 0..511
    const int isX = tid >> 8;              // 0 = h-team, 1 = x-team
    const int ttid = tid & 255;
    const int twave = ttid >> 6;           // gate 0..3
    const int lane = tid & 63;
    const int ln15 = lane & 15, lhi = lane >> 4;

    const unsigned short* Wl = layer ? W1 : W0;
    const float* bias = layer ? bias1 : bias0;
    unsigned short* hown = layer ? h1buf : h0buf;

    __shared__ Smem sm;
    unsigned short* mytile = isX ? sm.ax : sm.ah;

    // team weight panel (own K-part): 32 x bf16x8 = 128 VGPRs
    const unsigned short* Bb =
        Wl + (size_t)(twave * 1024 + j0 + ln15) * 2048 + (isX ? 0 : 1024) + lhi * 8;
    bf16x8 wreg[32];
#pragma unroll
    for (int k = 0; k < 32; ++k) wreg[k] = *(const bf16x8*)(Bb + k * 32);

    // epilogue mapping: all 512 threads, 1 element each: (bl, jj)
    const int bl = tid >> 4;               // 0..31
    const int jj = tid & 15;
    const int colg = j0 + jj;
    const float b_f = bias[colg], b_w = bias[1024 + colg];
    const float b_i = bias[2048 + colg], b_m = bias[3072 + colg];
    const int hoff = ((bl >> 4) << 14) + ((colg >> 5) << 9) +
                     ((((colg >> 3) & 3) << 4) + (bl & 15)) * 8 + (colg & 7);
    float creg = 0.f;

    const int P = T + 3;
    for (int p = 0; p < P; ++p) {
        const int tx = layer ? (p - 2) : p;
        const int th = layer ? (p - 3) : (p - 1);
        const bool actx = (tx >= 0) && (tx < T);
        const bool acth = (th >= 0) && (th < T);
        const bool myact = isX ? actx : acth;

        // ---- team-specific spin (L0-x never spins: seqb has no deps) ----
        if (p > 0 && myact && !(isX && layer == 0)) {
            const unsigned int tgt = (unsigned int)p;
            const unsigned int* f = &flags[(isX ? 0 : layer * 128) + (tid & 127)];
            while (ld32c(f) < tgt) __builtin_amdgcn_s_sleep(1);
        }

        // ---- stage own A-tile ----
        if (myact) {
            StageRegs s;
            if (isX) {
                if (layer == 0) {
                    if (SEQB) {
                        stage_issue_plain(s, seqb + ((size_t)tx * 2 + btile) * 32768, ttid);
                        stage_write(s, sm.ax, ttid);
                    }
                    // !SEQB: direct-from-fp32 path in the pass below
                } else {
                    stage_issue(s, h0buf + (size_t)((tx & 1) * 2 + btile) * 32768, ttid);
                    stage_write(s, sm.ax, ttid);
                }
            } else {
                // own-layer h[th-1]; (th-1)&1 == 1 when th==0 -> zeroed buffer
                stage_issue(s, hown + (size_t)(((th - 1) & 1) * 2 + btile) * 32768, ttid);
                stage_write(s, sm.ah, ttid);
            }
        }
        __syncthreads();  // SYNC A: tiles visible; spins joined

        // ---- pass: 64 MFMAs (M=32 via 2 accs, N=16, K=1024) ----
        if (myact) {
            f32x4 acc0 = {0.f, 0.f, 0.f, 0.f};
            f32x4 acc1 = {0.f, 0.f, 0.f, 0.f};
            if (isX && layer == 0 && !SEQB) {
                const float* a0f = seq + ((size_t)(brow + ln15) * T + tx) * 1024 + lhi * 8;
                const float* a1f = a0f + (size_t)16 * T * 1024;
#pragma unroll
                for (int kk = 0; kk < 32; ++kk) {
                    float4 l0 = ((const float4*)a0f)[0], h0v = ((const float4*)a0f)[1];
                    float4 l1 = ((const float4*)a1f)[0], h1v = ((const float4*)a1f)[1];
                    bf16x8 av0 = cvt8(l0, h0v), av1 = cvt8(l1, h1v);
                    acc0 = __builtin_amdgcn_mfma_f32_16x16x32_bf16(av0, wreg[kk], acc0, 0, 0, 0);
                    acc1 = __builtin_amdgcn_mfma_f32_16x16x32_bf16(av1, wreg[kk], acc1, 0, 0, 0);
                    a0f += 32; a1f += 32;
                }
            } else {
                const unsigned short* tile = mytile;
                if (!isX) __builtin_amdgcn_s_setprio(1);  // T5: favor the latency chain
#pragma unroll
                for (int kk = 0; kk < 32; ++kk) {
                    bf16x8 av0 = *(const bf16x8*)(tile + kk * 512 + lane * 8);
                    bf16x8 av1 = *(const bf16x8*)(tile + 16384 + kk * 512 + lane * 8);
                    acc0 = __builtin_amdgcn_mfma_f32_16x16x32_bf16(av0, wreg[kk], acc0, 0, 0, 0);
                    acc1 = __builtin_amdgcn_mfma_f32_16x16x32_bf16(av1, wreg[kk], acc1, 0, 0, 0);
                }
                if (!isX) __builtin_amdgcn_s_setprio(0);
            }
            // gate-exchange write (D layout: col=lane&15, row=(lane>>4)*4+reg)
            float* zd = isX ? &sm.zx[tx & 1][twave][0][0] : &sm.zh[twave][0][0];
#pragma unroll
            for (int rr = 0; rr < 4; ++rr) {
                zd[(4 * lhi + rr) * 16 + ln15] = acc0[rr];
                zd[(16 + 4 * lhi + rr) * 16 + ln15] = acc1[rr];
            }
        }
        __syncthreads();  // SYNC B: zh (this phase) + zx (prev phase) readable

        // ---- epilogue: all 512 threads, 1 element each ----
        if (acth) {
            const int zb = th & 1;
            float zf = sm.zh[0][bl][jj] + sm.zx[zb][0][bl][jj] + b_f;
            float zw = sm.zh[1][bl][jj] + sm.zx[zb][1][bl][jj] + b_w;
            float zi = sm.zh[2][bl][jj] + sm.zx[zb][2][bl][jj] + b_i;
            float zm = sm.zh[3][bl][jj] + sm.zx[zb][3][bl][jj] + b_m;
            float cn = creg * sigm(zf) + sigm(zw) * tanh_f(zi);
            float h = tanh_f(cn) * sigm(zm);
            creg = cn;
            unsigned short* tb = hown + (size_t)((th & 1) * 2 + btile) * 32768;
            st16c(tb + hoff, f2bf(h));
            if (layer && th == T - 1) out[(brow + bl) * 1024 + colg] = h;
        }

        // ---- publish phase completion ----
        if (p < P - 1) {
            __syncthreads();  // SYNC C: drains vmcnt (h-stores LLC-visible)
            if (tid == 0) st32c(&flags[bid], (unsigned int)(p + 1));
        }
    }
}

// ---------------------------------------------------------------------------
extern "C" void kernel_launch(void* const* d_in, const int* in_sizes, int n_in,
                              void* d_out, int out_size, void* d_ws, size_t ws_size,
                              hipStream_t stream) {
    const float* seq = (const float*)d_in[0];
    const float* Wx0 = (const float*)d_in[1];
    const float* Wh0 = (const float*)d_in[2];
    const float* b0 = (const float*)d_in[3];
    const float* Wx1 = (const float*)d_in[4];
    const float* Wh1 = (const float*)d_in[5];
    const float* b1 = (const float*)d_in[6];
    float* out = (float*)d_out;
    char* ws = (char*)d_ws;
    const int T = 512;

    const size_t WBYTES = (size_t)4096 * 2048 * 2;         // 16.78 MB per layer
    const size_t SEQB_BYTES = (size_t)512 * 2 * 32768 * 2; // 67.1 MB (tile-major)
    const size_t H0_BYTES = 2 * 2 * 65536;                  // 2 bufs x 2 btiles
    const size_t H1_BYTES = 2 * 2 * 65536;
    const size_t STATE_BYTES = H0_BYTES + H1_BYTES + 1024;  // + flags

    size_t offSeqb = 2 * WBYTES;
    bool big = ws_size >= 2 * WBYTES + SEQB_BYTES + STATE_BYTES;
    size_t offState = big ? (offSeqb + SEQB_BYTES) : offSeqb;

    unsigned short* W0p = (unsigned short*)(ws);
    unsigned short* W1p = (unsigned short*)(ws + WBYTES);
    unsigned short* seqbp = (unsigned short*)(ws + offSeqb);
    unsigned short* h0p = (unsigned short*)(ws + offState);
    unsigned short* h1p = (unsigned short*)(ws + offState + H0_BYTES);
    unsigned int* flagsp = (unsigned int*)(ws + offState + H0_BYTES + H1_BYTES);

    hipLaunchKernelGGL(cvt_weights, dim3(8192), dim3(256), 0, stream,
                       Wx0, Wh0, Wx1, Wh1, W0p, W1p);
    if (big)
        hipLaunchKernelGGL(cvt_seq, dim3(T * 64), dim3(128), 0, stream, seq, seqbp, T);
    hipMemsetAsync(ws + offState, 0, STATE_BYTES, stream);

    int Tv = T;
    void* args[] = {&seq, &seqbp, &W0p, &W1p, &b0, &b1, &h0p, &h1p, &flagsp, &out, &Tv};
    if (big) {
        hipError_t e = hipLaunchCooperativeKernel((void*)lstm_persistent<true>,
                                                  dim3(256), dim3(512), args, 0, stream);
        if (e != hipSuccess) {
            // co-residency guaranteed by capacity (1 block/CU, 256 blocks);
            // the custom flag barrier needs no cooperative-launch semantics.
            hipLaunchKernelGGL((lstm_persistent<true>), dim3(256), dim3(512), 0, stream,
                               seq, seqbp, W0p, W1p, b0, b1, h0p, h1p, flagsp, out, Tv);
        }
    } else {
        hipError_t e = hipLaunchCooperativeKernel((void*)lstm_persistent<false>,
                                                  dim3(256), dim3(512), args, 0, stream);
        if (e != hipSuccess) {
            hipLaunchKernelGGL((lstm_persistent<false>), dim3(256), dim3(512), 0, stream,
                               seq, seqbp, W0p, W1p, b0, b1, h0p, h1p, flagsp, out, Tv);
        }
    }
}